// Round 5
// baseline (160.841 us; speedup 1.0000x reference)
//
#include <hip/hip_runtime.h>
#include <hip/hip_bf16.h>
#include <stdint.h>

#define B_DIM 8192
#define D_DIM 2048
#define U_DIM 2048
#define KWORDS 64            // bit path: 2048 bits = 64 u32 words

typedef int v4i  __attribute__((ext_vector_type(4)));
typedef int v16i __attribute__((ext_vector_type(16)));

// Async global->LDS DMA, 16B per lane. LDS dest is wave-uniform base + lane*16;
// global src may be per-lane arbitrary (we fold the bank swizzle there).
__device__ __forceinline__ void load_lds16(const char* g, char* l) {
    __builtin_amdgcn_global_load_lds(
        (const __attribute__((address_space(1))) unsigned int*)g,
        (__attribute__((address_space(3))) unsigned int*)l,
        16, 0, 0);
}

// Counted vmem wait: never drain to 0 in the main loop (T4).
#define WAITVM(n) asm volatile("s_waitcnt vmcnt(" #n ")" ::: "memory")
#define SBAR      __builtin_amdgcn_s_barrier()

// ======================= i8 MFMA PATH =======================

// x [B][D] f32 -> xi [B][D] i8 (+1/-1). float4 in, packed u32 out. Coalesced.
__global__ void pack_x_i8(const float* __restrict__ x, char* __restrict__ xi) {
    int idx = blockIdx.x * 256 + threadIdx.x;
    float4 v = ((const float4*)x)[idx];
    unsigned b0 = (v.x >= 0.f) ? 0x01u : 0xFFu;
    unsigned b1 = (v.y >= 0.f) ? 0x01u : 0xFFu;
    unsigned b2 = (v.z >= 0.f) ? 0x01u : 0xFFu;
    unsigned b3 = (v.w >= 0.f) ? 0x01u : 0xFFu;
    ((unsigned*)xi)[idx] = b0 | (b1 << 8) | (b2 << 16) | (b3 << 24);
}

// k [D][U] f32 -> kt [U][D] i8 (+1/-1), transposed via LDS 64x64 tile.
__global__ void pack_kt_i8(const float* __restrict__ k, char* __restrict__ kt) {
    __shared__ float tile[64][65];
    const int j0 = (blockIdx.x & 31) * 64;   // U tile
    const int d0 = (blockIdx.x >> 5) * 64;   // D tile
    const int tid = threadIdx.x;
    const int lane = tid & 63;
    const int wv = tid >> 6;
    for (int i = 0; i < 16; i++) {
        int row = i * 4 + wv;
        tile[row][lane] = k[(size_t)(d0 + row) * U_DIM + j0 + lane];
    }
    __syncthreads();
    const int u = tid >> 2;          // 0..63 output row (unit)
    const int g = tid & 3;           // 16-byte group along D
    union { char c[16]; int4 v; } pk;
#pragma unroll
    for (int j = 0; j < 16; j++)
        pk.c[j] = (tile[g * 16 + j][u] >= 0.f) ? (char)1 : (char)-1;
    *(int4*)(kt + (size_t)(j0 + u) * D_DIM + d0 + g * 16) = pk.v;
}

// out[i][j] = sum_k xi[i][k]*kt[j][k] + bias[j], exact in i32.
//
// R4 (resubmitted R5: prior bench was a container-level infra failure; kernel
// audited for hang mechanisms - barrier divergence: none; vmcnt counts:
// consistent at every wait; buffer-reuse race: excluded by lgkm FIFO + SBAR;
// VGPR budget ~430 < 512 at 1 wave/SIMD).
//
// MFMA:DS-ratio fix. 256x256 block, 256 thr = 4 waves (2x2 grid of
// 128x128 wave tiles, Mr=Nr=4). Per K-tile per CU: 64 ds_read_b128 (~768cy)
// vs 128 MFMA (~1170cy) -> MFMA-bound (R3's 128x64 tiles were 96 reads vs
// 128 MFMA -> DS-bound and phase-serialized).
// With 1 wave/SIMD, overlap is pure ILP: REGISTER double-buffered fragments
// (named even/odd sets, rule #20), frags for tile t+1 ds_read BEFORE the
// MFMA cluster of tile t. The MFMA cluster waits on nothing (its frags
// landed last iteration; lgkm FIFO => already drained). One s_barrier/tile:
//   iter t: WAITVM(8)  (tile t+1 landed, own; staged 2 iters ago)
//           SBAR       (t+1 landed chip-wide; all waves past MFMA(t-1) =>
//                       their fr(t-1) LDS reads drained => buf[(t-1)&3] free)
//           stage(t+3 -> buf[(t+3)&3])   (VMEM streams under MFMA)
//           ds_read fr_next <- buf[(t+1)&3]  (DS streams under MFMA)
//           32x mfma_i32_32x32x32_i8 on fr_cur  (no lgkm/vmem stall)
// vmcnt never 0 in the main loop; peeled tail 8 -> 8 -> 0.
//
// Bank swizzle folded into the GLOBAL source (LDS dest stays linear for
// global_load_lds): within each 128B row-pair, 16B slot s <- s ^ (pair&7).
// Grid = 256 blocks = 1/CU; XCD swizzle: contiguous 32-block chunk per XCD.
__launch_bounds__(256, 1)
__global__ void gemm_i8(const char* __restrict__ xi,   // [8192][2048]
                        const char* __restrict__ kt,   // [2048][2048]
                        const float* __restrict__ bias,
                        float* __restrict__ out) {
    __shared__ uint4 lds[4][2048];   // [buf][ A:slots 0..1023 | B:1024..2047 ]

    const int tid  = threadIdx.x;
    const int lane = tid & 63;
    const int w    = tid >> 6;       // 4 waves
    const int m    = lane & 31;
    const int half = lane >> 5;

    // XCD-aware swizzle (nwg=256, 8 XCDs, 32 blocks/chunk; bijective)
    const int bid = blockIdx.x;
    const int swz = ((bid & 7) << 5) | (bid >> 3);
    const int bx  = swz & 7;         // U tile index [0,8)
    const int by  = swz >> 3;        // B tile index [0,32)
    const int rows0 = by << 8;
    const int cols0 = bx << 8;

    const int wr = (w >> 1) << 7;    // wave row offset: 0 or 128
    const int wc = (w & 1) << 7;     // wave col offset: 0 or 128

    v16i acc[4][4];
#pragma unroll
    for (int mi = 0; mi < 4; ++mi)
#pragma unroll
        for (int nj = 0; nj < 4; ++nj)
#pragma unroll
            for (int i = 0; i < 16; ++i) acc[mi][nj][i] = 0;

    const char* abase = xi + (size_t)rows0 * D_DIM;
    const char* bbase = kt + (size_t)cols0 * D_DIM;

    // --- staging precompute: 4 A-slots + 4 B-slots per thread ---
    // flat slot s in [0,1024): row = s>>2, g = s&3. Storage slot (p=row>>1,
    // sp=((row&1)<<2)|g) holds global slot sl = sp ^ (p&7) -> row/group.
    int   sbase[4];
    size_t goff0[4];
#pragma unroll
    for (int j = 0; j < 4; ++j) {
        sbase[j] = (w << 6) + (j << 8);          // wave-uniform LDS slot base
        const int s   = sbase[j] + lane;
        const int row = s >> 2, g = s & 3;
        const int p   = row >> 1;
        const int sl  = ((((row & 1) << 2) | g) ^ (p & 7));
        const int gr  = (p << 1) | (sl >> 2);
        const int gg  = sl & 3;
        goff0[j] = (size_t)gr * D_DIM + (size_t)(gg << 4);
    }

    auto stage = [&](int t, int buf) {
        const size_t kof = (size_t)t << 6;       // t * 64 bytes along K
#pragma unroll
        for (int j = 0; j < 4; ++j)
            load_lds16(abase + goff0[j] + kof, (char*)&lds[buf][sbase[j]]);
#pragma unroll
        for (int j = 0; j < 4; ++j)
            load_lds16(bbase + goff0[j] + kof, (char*)&lds[buf][1024 + sbase[j]]);
    };

    // --- fragment read offsets (loop-invariant; swizzled) ---
    // logical: row rl, 16B group gl = kk*2+half -> byte (rl>>1)*128 + st*16
    int aoff[4][2], boff[4][2];
#pragma unroll
    for (int mi = 0; mi < 4; ++mi)
#pragma unroll
        for (int kk = 0; kk < 2; ++kk) {
            const int rl = wr + mi * 32 + m;
            const int gl = kk * 2 + half;
            const int p  = rl >> 1;
            const int st = ((((rl & 1) << 2) | gl) ^ (p & 7));
            aoff[mi][kk] = (p << 7) + (st << 4);
        }
#pragma unroll
    for (int nj = 0; nj < 4; ++nj)
#pragma unroll
        for (int kk = 0; kk < 2; ++kk) {
            const int rl = wc + nj * 32 + m;
            const int gl = kk * 2 + half;
            const int p  = rl >> 1;
            const int st = ((((rl & 1) << 2) | gl) ^ (p & 7));
            boff[nj][kk] = 16384 + (p << 7) + (st << 4);
        }

    struct Frag { v4i a[4][2]; v4i b[4][2]; };
    Frag frE, frO;                    // named double-buffer (rule #20)

    auto readFrags = [&](Frag& f, int buf) {
        const char* Ls = (const char*)lds[buf];
#pragma unroll
        for (int kk = 0; kk < 2; ++kk) {
#pragma unroll
            for (int mi = 0; mi < 4; ++mi)
                f.a[mi][kk] = *(const v4i*)(Ls + aoff[mi][kk]);
#pragma unroll
            for (int nj = 0; nj < 4; ++nj)
                f.b[nj][kk] = *(const v4i*)(Ls + boff[nj][kk]);
        }
    };
    auto mmaTile = [&](const Frag& f) {
#pragma unroll
        for (int kk = 0; kk < 2; ++kk)
#pragma unroll
            for (int mi = 0; mi < 4; ++mi)
#pragma unroll
                for (int nj = 0; nj < 4; ++nj)
                    acc[mi][nj] = __builtin_amdgcn_mfma_i32_32x32x32_i8(
                        f.a[mi][kk], f.b[nj][kk], acc[mi][nj], 0, 0, 0);
    };

    // prologue: stage tiles 0,1,2 (24 loads/thread in flight)
    stage(0, 0); stage(1, 1); stage(2, 2);
    WAITVM(16);                       // tile 0 landed (own)
    SBAR;                             // ... chip-wide
    readFrags(frE, 0);                // frags for tile 0

    // main loop: tiles 0..27 (2 per iteration, even->frE odd->frO)
#pragma unroll 1
    for (int t = 0; t < 28; t += 2) {
        // tile t (even): compute frE, prefetch frO <- tile t+1
        WAITVM(8); SBAR;
        stage(t + 3, (t + 3) & 3);
        readFrags(frO, (t + 1) & 3);
        mmaTile(frE);
        // tile t+1 (odd): compute frO, prefetch frE <- tile t+2
        WAITVM(8); SBAR;
        stage(t + 4, (t + 4) & 3);
        readFrags(frE, (t + 2) & 3);
        mmaTile(frO);
    }
    // t=28: compute frE, stage tile 31, prefetch frO <- 29
    WAITVM(8); SBAR; stage(31, 3); readFrags(frO, 1); mmaTile(frE);
    // t=29: compute frO, prefetch frE <- 30
    WAITVM(8); SBAR; readFrags(frE, 2); mmaTile(frO);
    // t=30: compute frE, prefetch frO <- 31 (drain to 0: last tile)
    WAITVM(0); SBAR; readFrags(frO, 3); mmaTile(frE);
    // t=31
    mmaTile(frO);

    // C/D 32x32 layout (HW-verified R6): col = lane&31, row = (reg&3)+8*(reg>>2)+4*half
#pragma unroll
    for (int mi = 0; mi < 4; ++mi)
#pragma unroll
        for (int nj = 0; nj < 4; ++nj) {
            const int n = cols0 + wc + nj * 32 + m;
            const float bb = bias[n];
#pragma unroll
            for (int reg = 0; reg < 16; ++reg) {
                const int row = (reg & 3) + 8 * (reg >> 2) + 4 * half;
                const size_t grow = (size_t)(rows0 + wr + mi * 32 + row);
                out[grow * U_DIM + n] = (float)acc[mi][nj][reg] + bb;
            }
        }
}

// ======================= BIT-PATH FALLBACK (R5, proven) =======================

__global__ void pack_x_kernel(const float* __restrict__ x,
                              unsigned long long* __restrict__ xb) {
    const int gwave = (blockIdx.x * blockDim.x + threadIdx.x) >> 6;
    const int lane  = threadIdx.x & 63;
    const size_t base = (size_t)gwave * 256;
    float v0 = x[base + lane];
    float v1 = x[base + 64 + lane];
    float v2 = x[base + 128 + lane];
    float v3 = x[base + 192 + lane];
    unsigned long long m0 = __ballot(v0 >= 0.0f);
    unsigned long long m1 = __ballot(v1 >= 0.0f);
    unsigned long long m2 = __ballot(v2 >= 0.0f);
    unsigned long long m3 = __ballot(v3 >= 0.0f);
    if (lane == 0) {
        ulonglong2* p = (ulonglong2*)(xb + (base >> 6));
        ulonglong2 a; a.x = m0; a.y = m1;
        ulonglong2 b; b.x = m2; b.y = m3;
        p[0] = a;
        p[1] = b;
    }
}

__global__ void pack_k_kernel(const float* __restrict__ k,
                              unsigned long long* __restrict__ kb) {
    __shared__ float tile[64][65];
    const int j0 = (blockIdx.x & 31) * 64;
    const int d0 = (blockIdx.x >> 5) * 64;
    const int tid  = threadIdx.x;
    const int lane = tid & 63;
    const int wv   = tid >> 6;
    for (int i = 0; i < 16; i++) {
        int row = i * 4 + wv;
        tile[row][lane] = k[(size_t)(d0 + row) * U_DIM + j0 + lane];
    }
    __syncthreads();
    for (int c = wv * 16; c < wv * 16 + 16; c++) {
        float v = tile[lane][c];
        unsigned long long m = __ballot(v >= 0.0f);
        if (lane == 0) kb[(size_t)(j0 + c) * (D_DIM / 64) + (d0 >> 6)] = m;
    }
}

__launch_bounds__(512)
__global__ void bgemm_kernel(const unsigned int* __restrict__ xb,
                             const unsigned int* __restrict__ kb,
                             const float* __restrict__ bias,
                             float* __restrict__ out) {
    __shared__ unsigned int xs[128 * KWORDS];
    __shared__ unsigned int ks[128 * KWORDS];
    const int bx  = blockIdx.x;
    const int by  = blockIdx.y;
    const int tid = threadIdx.x;
    const uint4* xsrc = (const uint4*)(xb + (size_t)(by * 128) * KWORDS);
    const uint4* ksrc = (const uint4*)(kb + (size_t)(bx * 128) * KWORDS);
#pragma unroll
    for (int i = 0; i < 4; i++) {
        int flat = tid + i * 512;
        int r    = flat >> 4;
        int g    = flat & 15;
        int sg   = g ^ ((r >> 3) & 7);
        uint4 xv = xsrc[flat];
        uint4 kv = ksrc[flat];
        *((uint4*)&xs[r * KWORDS + sg * 4]) = xv;
        *((uint4*)&ks[r * KWORDS + sg * 4]) = kv;
    }
    __syncthreads();
    const int tr   = (tid >> 4) * 4;
    const int tc   = (tid & 15) * 8;
    const int xswz = ((tid >> 4) >> 1) & 7;
    const int ksw  = tid & 7;
    int acc[4][8] = {};
    for (int w4 = 0; w4 < 16; w4++) {
        const int xcol = (w4 ^ xswz) * 4;
        const int kcol = (w4 ^ ksw) * 4;
        uint4 xv[4], kv[8];
#pragma unroll
        for (int r = 0; r < 4; r++) xv[r] = *((const uint4*)&xs[(tr + r) * KWORDS + xcol]);
#pragma unroll
        for (int c = 0; c < 8; c++) kv[c] = *((const uint4*)&ks[(tc + c) * KWORDS + kcol]);
#pragma unroll
        for (int r = 0; r < 4; r++)
#pragma unroll
            for (int c = 0; c < 8; c++) {
                acc[r][c] += __popc(xv[r].x ^ kv[c].x);
                acc[r][c] += __popc(xv[r].y ^ kv[c].y);
                acc[r][c] += __popc(xv[r].z ^ kv[c].z);
                acc[r][c] += __popc(xv[r].w ^ kv[c].w);
            }
    }
    const int row0 = by * 128 + tr;
    const int col0 = bx * 128 + tc;
    const float4 b0 = *((const float4*)&bias[col0]);
    const float4 b1 = *((const float4*)&bias[col0 + 4]);
#pragma unroll
    for (int r = 0; r < 4; r++) {
        float4 o0, o1;
        o0.x = (float)(D_DIM - 2 * acc[r][0]) + b0.x;
        o0.y = (float)(D_DIM - 2 * acc[r][1]) + b0.y;
        o0.z = (float)(D_DIM - 2 * acc[r][2]) + b0.z;
        o0.w = (float)(D_DIM - 2 * acc[r][3]) + b0.w;
        o1.x = (float)(D_DIM - 2 * acc[r][4]) + b1.x;
        o1.y = (float)(D_DIM - 2 * acc[r][5]) + b1.y;
        o1.z = (float)(D_DIM - 2 * acc[r][6]) + b1.z;
        o1.w = (float)(D_DIM - 2 * acc[r][7]) + b1.w;
        float* orow = &out[(size_t)(row0 + r) * U_DIM + col0];
        *((float4*)orow)       = o0;
        *((float4*)(orow + 4)) = o1;
    }
}

// ======================= launcher =======================

extern "C" void kernel_launch(void* const* d_in, const int* in_sizes, int n_in,
                              void* d_out, int out_size, void* d_ws, size_t ws_size,
                              hipStream_t stream) {
    const float* x    = (const float*)d_in[0];   // [8192][2048]
    const float* k    = (const float*)d_in[1];   // [2048][2048]
    const float* bias = (const float*)d_in[2];   // [2048]
    float* out = (float*)d_out;

    const size_t need_i8 = (size_t)B_DIM * D_DIM + (size_t)U_DIM * D_DIM; // ~21 MB
    if (ws_size >= need_i8) {
        char* xi = (char*)d_ws;                          // 16 MB
        char* kt = xi + (size_t)B_DIM * D_DIM;           // 4 MB
        pack_x_i8<<<(B_DIM * D_DIM) / 1024, 256, 0, stream>>>(x, xi);
        pack_kt_i8<<<32 * 32, 256, 0, stream>>>(k, kt);
        gemm_i8<<<256, 256, 0, stream>>>(xi, kt, bias, out);
    } else {
        unsigned long long* xbits = (unsigned long long*)d_ws;
        unsigned long long* kbits = (unsigned long long*)((char*)d_ws + (size_t)B_DIM * (D_DIM / 8));
        pack_x_kernel<<<(B_DIM * D_DIM) / 1024, 256, 0, stream>>>(x, xbits);
        pack_k_kernel<<<32 * 32, 256, 0, stream>>>(k, kbits);
        dim3 grid(U_DIM / 128, B_DIM / 128);
        bgemm_kernel<<<grid, 512, 0, stream>>>((const unsigned int*)xbits,
                                               (const unsigned int*)kbits, bias, out);
    }
}

// Round 6
// 159.655 us; speedup vs baseline: 1.0074x; 1.0074x over previous
//
#include <hip/hip_runtime.h>
#include <hip/hip_bf16.h>
#include <stdint.h>

#define B_DIM 8192
#define D_DIM 2048
#define U_DIM 2048
#define KWORDS 64            // bit path: 2048 bits = 64 u32 words

typedef int v4i  __attribute__((ext_vector_type(4)));
typedef int v16i __attribute__((ext_vector_type(16)));

// Async global->LDS DMA, 16B per lane. LDS dest is wave-uniform base + lane*16;
// global src may be per-lane arbitrary (we fold the bank swizzle there).
__device__ __forceinline__ void load_lds16(const char* g, char* l) {
    __builtin_amdgcn_global_load_lds(
        (const __attribute__((address_space(1))) unsigned int*)g,
        (__attribute__((address_space(3))) unsigned int*)l,
        16, 0, 0);
}

// Counted vmem wait: never drain to 0 in the main loop (T4).
#define WAITVM(n) asm volatile("s_waitcnt vmcnt(" #n ")" ::: "memory")
#define SBAR      __builtin_amdgcn_s_barrier()
// Pin per-phase interleave: 8 ds_read then 16 MFMA (T19 as structural fence).
#define SGB_PHASE do { \
    __builtin_amdgcn_sched_group_barrier(0x100, 8, 0);  \
    __builtin_amdgcn_sched_group_barrier(0x008, 16, 0); } while (0)

// ======================= i8 MFMA PATH =======================

// x [B][D] f32 -> xi [B][D] i8 (+1/-1). float4 in, packed u32 out. Coalesced.
__global__ void pack_x_i8(const float* __restrict__ x, char* __restrict__ xi) {
    int idx = blockIdx.x * 256 + threadIdx.x;
    float4 v = ((const float4*)x)[idx];
    unsigned b0 = (v.x >= 0.f) ? 0x01u : 0xFFu;
    unsigned b1 = (v.y >= 0.f) ? 0x01u : 0xFFu;
    unsigned b2 = (v.z >= 0.f) ? 0x01u : 0xFFu;
    unsigned b3 = (v.w >= 0.f) ? 0x01u : 0xFFu;
    ((unsigned*)xi)[idx] = b0 | (b1 << 8) | (b2 << 16) | (b3 << 24);
}

// k [D][U] f32 -> kt [U][D] i8 (+1/-1), transposed via LDS 64x64 tile.
__global__ void pack_kt_i8(const float* __restrict__ k, char* __restrict__ kt) {
    __shared__ float tile[64][65];
    const int j0 = (blockIdx.x & 31) * 64;   // U tile
    const int d0 = (blockIdx.x >> 5) * 64;   // D tile
    const int tid = threadIdx.x;
    const int lane = tid & 63;
    const int wv = tid >> 6;
    for (int i = 0; i < 16; i++) {
        int row = i * 4 + wv;
        tile[row][lane] = k[(size_t)(d0 + row) * U_DIM + j0 + lane];
    }
    __syncthreads();
    const int u = tid >> 2;          // 0..63 output row (unit)
    const int g = tid & 3;           // 16-byte group along D
    union { char c[16]; int4 v; } pk;
#pragma unroll
    for (int j = 0; j < 16; j++)
        pk.c[j] = (tile[g * 16 + j][u] >= 0.f) ? (char)1 : (char)-1;
    *(int4*)(kt + (size_t)(j0 + u) * D_DIM + d0 + g * 16) = pk.v;
}

// out[i][j] = sum_k xi[i][k]*kt[j][k] + bias[j], exact in i32.
//
// R6: lgkm-conservatism fix. R1/R2/R3/R5 all placed an asm-with-"memory"
// (WAITVM/SBAR) between ds_read issue and MFMA consumption; the compiler's
// waitcnt pass then loses count certainty and drains lgkmcnt(0) before each
// MFMA cluster -> DS and MFMA fully serialized (all rounds ~26-28% MfmaUtil,
// ~3100 cy/tile = DS 768 + MFMA 1170 summed + overhead).
//
// Geometry (R5, DS-minimal): 256x256 block, 256 thr = 4 waves, 2x2 grid of
// 128x128 wave tiles. Per tile per CU: 64 ds_read_b128 (768 cy) vs 128 MFMA
// (1170 cy). Per tile = 2 kk-phases, and each phase's reads+uses stay inside
// ONE clobber-free region:
//   boundary: WAITVM(8) (tile t+1 landed, own; staged 3 iters ago)
//             SBAR      (chip-wide; buf[(t-1)&3] fully consumed by all waves)
//             stage(t+3 -> buf[(t+3)&3])
//   phase A:  8x ds_read fO <- (tile t, kk1); 16x MFMA on fE (tile t, kk0)
//   phase B:  8x ds_read fE <- (tile t+1, kk0); 16x MFMA on fO
// Only fE's reads cross the boundary clobber (worst-case one conservative
// lgkm drain of ~380 cy/tile, vs ~1900 before). sched_group_barrier pins
// {DS_READ x8, MFMA x16} per phase so the scheduler can't sink the prefetch
// reads below the MFMAs. vmcnt counted (8), never 0 until the tail.
//
// Bank swizzle folded into the GLOBAL source (LDS dest stays linear for
// global_load_lds): within each 128B row-pair, 16B slot s <- s ^ (pair&7).
// Grid = 256 blocks = 1/CU; XCD swizzle: contiguous 32-block chunk per XCD.
__launch_bounds__(256, 1)
__global__ void gemm_i8(const char* __restrict__ xi,   // [8192][2048]
                        const char* __restrict__ kt,   // [2048][2048]
                        const float* __restrict__ bias,
                        float* __restrict__ out) {
    __shared__ uint4 lds[4][2048];   // [buf][ A:slots 0..1023 | B:1024..2047 ]

    const int tid  = threadIdx.x;
    const int lane = tid & 63;
    const int w    = tid >> 6;       // 4 waves
    const int m    = lane & 31;
    const int half = lane >> 5;

    // XCD-aware swizzle (nwg=256, 8 XCDs, 32 blocks/chunk; bijective)
    const int bid = blockIdx.x;
    const int swz = ((bid & 7) << 5) | (bid >> 3);
    const int bx  = swz & 7;         // U tile index [0,8)
    const int by  = swz >> 3;        // B tile index [0,32)
    const int rows0 = by << 8;
    const int cols0 = bx << 8;

    const int wr = (w >> 1) << 7;    // wave row offset: 0 or 128
    const int wc = (w & 1) << 7;     // wave col offset: 0 or 128

    v16i acc[4][4];
#pragma unroll
    for (int mi = 0; mi < 4; ++mi)
#pragma unroll
        for (int nj = 0; nj < 4; ++nj)
#pragma unroll
            for (int i = 0; i < 16; ++i) acc[mi][nj][i] = 0;

    const char* abase = xi + (size_t)rows0 * D_DIM;
    const char* bbase = kt + (size_t)cols0 * D_DIM;

    // --- staging precompute: 4 A-slots + 4 B-slots per thread ---
    // flat slot s in [0,1024): row = s>>2, g = s&3. Storage slot (p=row>>1,
    // sp=((row&1)<<2)|g) holds global slot sl = sp ^ (p&7) -> row/group.
    int   sbase[4];
    size_t goff0[4];
#pragma unroll
    for (int j = 0; j < 4; ++j) {
        sbase[j] = (w << 6) + (j << 8);          // wave-uniform LDS slot base
        const int s   = sbase[j] + lane;
        const int row = s >> 2, g = s & 3;
        const int p   = row >> 1;
        const int sl  = ((((row & 1) << 2) | g) ^ (p & 7));
        const int gr  = (p << 1) | (sl >> 2);
        const int gg  = sl & 3;
        goff0[j] = (size_t)gr * D_DIM + (size_t)(gg << 4);
    }

    auto stage = [&](int t, int buf) {
        const size_t kof = (size_t)t << 6;       // t * 64 bytes along K
#pragma unroll
        for (int j = 0; j < 4; ++j)
            load_lds16(abase + goff0[j] + kof, (char*)&lds[buf][sbase[j]]);
#pragma unroll
        for (int j = 0; j < 4; ++j)
            load_lds16(bbase + goff0[j] + kof, (char*)&lds[buf][1024 + sbase[j]]);
    };

    // --- fragment read offsets (loop-invariant; swizzled) ---
    // logical: row rl, 16B group gl = kk*2+half -> byte (rl>>1)*128 + st*16
    int aoff[4][2], boff[4][2];
#pragma unroll
    for (int mi = 0; mi < 4; ++mi)
#pragma unroll
        for (int kk = 0; kk < 2; ++kk) {
            const int rl = wr + mi * 32 + m;
            const int gl = kk * 2 + half;
            const int p  = rl >> 1;
            const int st = ((((rl & 1) << 2) | gl) ^ (p & 7));
            aoff[mi][kk] = (p << 7) + (st << 4);
        }
#pragma unroll
    for (int nj = 0; nj < 4; ++nj)
#pragma unroll
        for (int kk = 0; kk < 2; ++kk) {
            const int rl = wc + nj * 32 + m;
            const int gl = kk * 2 + half;
            const int p  = rl >> 1;
            const int st = ((((rl & 1) << 2) | gl) ^ (p & 7));
            boff[nj][kk] = 16384 + (p << 7) + (st << 4);
        }

    // fE always holds kk=0 fragments, fO always kk=1 (named sets, rule #20)
    struct FragK { v4i a[4]; v4i b[4]; };
    FragK fE, fO;

    auto readK = [&](FragK& f, int buf, int kk) {
        const char* Ls = (const char*)lds[buf];
#pragma unroll
        for (int mi = 0; mi < 4; ++mi)
            f.a[mi] = *(const v4i*)(Ls + aoff[mi][kk]);
#pragma unroll
        for (int nj = 0; nj < 4; ++nj)
            f.b[nj] = *(const v4i*)(Ls + boff[nj][kk]);
    };
    auto mma16 = [&](const FragK& f) {
#pragma unroll
        for (int mi = 0; mi < 4; ++mi)
#pragma unroll
            for (int nj = 0; nj < 4; ++nj)
                acc[mi][nj] = __builtin_amdgcn_mfma_i32_32x32x32_i8(
                    f.a[mi], f.b[nj], acc[mi][nj], 0, 0, 0);
    };

    // prologue: stage tiles 0,1,2 (24 loads/thread in flight)
    stage(0, 0); stage(1, 1); stage(2, 2);
    WAITVM(8);                        // tiles 0 AND 1 landed (own)
    SBAR;                             // ... chip-wide
    readK(fE, 0, 0);                  // tile 0, kk0

    // main loop: tiles 0..28; stage t+3
#pragma unroll 1
    for (int t = 0; t < 29; ++t) {
        WAITVM(8);                    // tile t+1 landed (own)
        SBAR;                         // chip-wide; buf[(t-1)&3] consumed
        stage(t + 3, (t + 3) & 3);
        // phase A: prefetch kk1, compute kk0
        readK(fO, t & 3, 1);
        mma16(fE);
        SGB_PHASE;
        // phase B: prefetch next tile's kk0, compute kk1
        readK(fE, (t + 1) & 3, 0);
        mma16(fO);
        SGB_PHASE;
    }
    // t=29 (buf 1): tile 30 landed after WAITVM(8)
    WAITVM(8); SBAR;
    readK(fO, 1, 1); mma16(fE); SGB_PHASE;
    readK(fE, 2, 0); mma16(fO); SGB_PHASE;
    // t=30 (buf 2): tile 31 landed after WAITVM(0)
    WAITVM(0); SBAR;
    readK(fO, 2, 1); mma16(fE); SGB_PHASE;
    readK(fE, 3, 0); mma16(fO); SGB_PHASE;
    // t=31 (buf 3)
    readK(fO, 3, 1); mma16(fE); SGB_PHASE;
    mma16(fO);

    // C/D 32x32 layout (HW-verified R6): col = lane&31, row = (reg&3)+8*(reg>>2)+4*half
#pragma unroll
    for (int mi = 0; mi < 4; ++mi)
#pragma unroll
        for (int nj = 0; nj < 4; ++nj) {
            const int n = cols0 + wc + nj * 32 + m;
            const float bb = bias[n];
#pragma unroll
            for (int reg = 0; reg < 16; ++reg) {
                const int row = (reg & 3) + 8 * (reg >> 2) + 4 * half;
                const size_t grow = (size_t)(rows0 + wr + mi * 32 + row);
                out[grow * U_DIM + n] = (float)acc[mi][nj][reg] + bb;
            }
        }
}

// ======================= BIT-PATH FALLBACK (R5, proven) =======================

__global__ void pack_x_kernel(const float* __restrict__ x,
                              unsigned long long* __restrict__ xb) {
    const int gwave = (blockIdx.x * blockDim.x + threadIdx.x) >> 6;
    const int lane  = threadIdx.x & 63;
    const size_t base = (size_t)gwave * 256;
    float v0 = x[base + lane];
    float v1 = x[base + 64 + lane];
    float v2 = x[base + 128 + lane];
    float v3 = x[base + 192 + lane];
    unsigned long long m0 = __ballot(v0 >= 0.0f);
    unsigned long long m1 = __ballot(v1 >= 0.0f);
    unsigned long long m2 = __ballot(v2 >= 0.0f);
    unsigned long long m3 = __ballot(v3 >= 0.0f);
    if (lane == 0) {
        ulonglong2* p = (ulonglong2*)(xb + (base >> 6));
        ulonglong2 a; a.x = m0; a.y = m1;
        ulonglong2 b; b.x = m2; b.y = m3;
        p[0] = a;
        p[1] = b;
    }
}

__global__ void pack_k_kernel(const float* __restrict__ k,
                              unsigned long long* __restrict__ kb) {
    __shared__ float tile[64][65];
    const int j0 = (blockIdx.x & 31) * 64;
    const int d0 = (blockIdx.x >> 5) * 64;
    const int tid  = threadIdx.x;
    const int lane = tid & 63;
    const int wv   = tid >> 6;
    for (int i = 0; i < 16; i++) {
        int row = i * 4 + wv;
        tile[row][lane] = k[(size_t)(d0 + row) * U_DIM + j0 + lane];
    }
    __syncthreads();
    for (int c = wv * 16; c < wv * 16 + 16; c++) {
        float v = tile[lane][c];
        unsigned long long m = __ballot(v >= 0.0f);
        if (lane == 0) kb[(size_t)(j0 + c) * (D_DIM / 64) + (d0 >> 6)] = m;
    }
}

__launch_bounds__(512)
__global__ void bgemm_kernel(const unsigned int* __restrict__ xb,
                             const unsigned int* __restrict__ kb,
                             const float* __restrict__ bias,
                             float* __restrict__ out) {
    __shared__ unsigned int xs[128 * KWORDS];
    __shared__ unsigned int ks[128 * KWORDS];
    const int bx  = blockIdx.x;
    const int by  = blockIdx.y;
    const int tid = threadIdx.x;
    const uint4* xsrc = (const uint4*)(xb + (size_t)(by * 128) * KWORDS);
    const uint4* ksrc = (const uint4*)(kb + (size_t)(bx * 128) * KWORDS);
#pragma unroll
    for (int i = 0; i < 4; i++) {
        int flat = tid + i * 512;
        int r    = flat >> 4;
        int g    = flat & 15;
        int sg   = g ^ ((r >> 3) & 7);
        uint4 xv = xsrc[flat];
        uint4 kv = ksrc[flat];
        *((uint4*)&xs[r * KWORDS + sg * 4]) = xv;
        *((uint4*)&ks[r * KWORDS + sg * 4]) = kv;
    }
    __syncthreads();
    const int tr   = (tid >> 4) * 4;
    const int tc   = (tid & 15) * 8;
    const int xswz = ((tid >> 4) >> 1) & 7;
    const int ksw  = tid & 7;
    int acc[4][8] = {};
    for (int w4 = 0; w4 < 16; w4++) {
        const int xcol = (w4 ^ xswz) * 4;
        const int kcol = (w4 ^ ksw) * 4;
        uint4 xv[4], kv[8];
#pragma unroll
        for (int r = 0; r < 4; r++) xv[r] = *((const uint4*)&xs[(tr + r) * KWORDS + xcol]);
#pragma unroll
        for (int c = 0; c < 8; c++) kv[c] = *((const uint4*)&ks[(tc + c) * KWORDS + kcol]);
#pragma unroll
        for (int r = 0; r < 4; r++)
#pragma unroll
            for (int c = 0; c < 8; c++) {
                acc[r][c] += __popc(xv[r].x ^ kv[c].x);
                acc[r][c] += __popc(xv[r].y ^ kv[c].y);
                acc[r][c] += __popc(xv[r].z ^ kv[c].z);
                acc[r][c] += __popc(xv[r].w ^ kv[c].w);
            }
    }
    const int row0 = by * 128 + tr;
    const int col0 = bx * 128 + tc;
    const float4 b0 = *((const float4*)&bias[col0]);
    const float4 b1 = *((const float4*)&bias[col0 + 4]);
#pragma unroll
    for (int r = 0; r < 4; r++) {
        float4 o0, o1;
        o0.x = (float)(D_DIM - 2 * acc[r][0]) + b0.x;
        o0.y = (float)(D_DIM - 2 * acc[r][1]) + b0.y;
        o0.z = (float)(D_DIM - 2 * acc[r][2]) + b0.z;
        o0.w = (float)(D_DIM - 2 * acc[r][3]) + b0.w;
        o1.x = (float)(D_DIM - 2 * acc[r][4]) + b1.x;
        o1.y = (float)(D_DIM - 2 * acc[r][5]) + b1.y;
        o1.z = (float)(D_DIM - 2 * acc[r][6]) + b1.z;
        o1.w = (float)(D_DIM - 2 * acc[r][7]) + b1.w;
        float* orow = &out[(size_t)(row0 + r) * U_DIM + col0];
        *((float4*)orow)       = o0;
        *((float4*)(orow + 4)) = o1;
    }
}

// ======================= launcher =======================

extern "C" void kernel_launch(void* const* d_in, const int* in_sizes, int n_in,
                              void* d_out, int out_size, void* d_ws, size_t ws_size,
                              hipStream_t stream) {
    const float* x    = (const float*)d_in[0];   // [8192][2048]
    const float* k    = (const float*)d_in[1];   // [2048][2048]
    const float* bias = (const float*)d_in[2];   // [2048]
    float* out = (float*)d_out;

    const size_t need_i8 = (size_t)B_DIM * D_DIM + (size_t)U_DIM * D_DIM; // ~21 MB
    if (ws_size >= need_i8) {
        char* xi = (char*)d_ws;                          // 16 MB
        char* kt = xi + (size_t)B_DIM * D_DIM;           // 4 MB
        pack_x_i8<<<(B_DIM * D_DIM) / 1024, 256, 0, stream>>>(x, xi);
        pack_kt_i8<<<32 * 32, 256, 0, stream>>>(k, kt);
        gemm_i8<<<256, 256, 0, stream>>>(xi, kt, bias, out);
    } else {
        unsigned long long* xbits = (unsigned long long*)d_ws;
        unsigned long long* kbits = (unsigned long long*)((char*)d_ws + (size_t)B_DIM * (D_DIM / 8));
        pack_x_kernel<<<(B_DIM * D_DIM) / 1024, 256, 0, stream>>>(x, xbits);
        pack_k_kernel<<<32 * 32, 256, 0, stream>>>(k, kbits);
        dim3 grid(U_DIM / 128, B_DIM / 128);
        bgemm_kernel<<<grid, 512, 0, stream>>>((const unsigned int*)xbits,
                                               (const unsigned int*)kbits, bias, out);
    }
}